// Round 6
// baseline (258.857 us; speedup 1.0000x reference)
//
#include <hip/hip_runtime.h>
#include <hip/hip_bf16.h>

#define M_TOTAL 65536
#define N_TOTAL 1024
#define K_TOTAL 1024
#define BM 256
#define BN 256
#define BK 64
#define NT 16

typedef __attribute__((ext_vector_type(4))) int   i32x4;

typedef __attribute__((address_space(3))) void lds_vp;
typedef const __attribute__((address_space(1))) void glb_vp;

#define BAR()    asm volatile("s_barrier" ::: "memory")
#define WAITV8() asm volatile("s_waitcnt vmcnt(8)" ::: "memory")
#define WAITV0() asm volatile("s_waitcnt vmcnt(0)" ::: "memory")
#define WAITL0() asm volatile("s_waitcnt lgkmcnt(0)" ::: "memory")

#define MAGIC 12582912.0f   // 1.5 * 2^23: g = v + MAGIC -> low byte = (int8)rint(v)

static __device__ __forceinline__ unsigned fbits(float f) {
    union { float f; unsigned u; } c; c.f = f; return c.u;
}
// pack low bytes of 4 magic-biased floats into one dword (b0|b1<<8|b2<<16|b3<<24)
static __device__ __forceinline__ unsigned pk4(float g0, float g1, float g2, float g3) {
    unsigned p01 = __builtin_amdgcn_perm(fbits(g1), fbits(g0), 0x0C0C0400u);
    unsigned p23 = __builtin_amdgcn_perm(fbits(g3), fbits(g2), 0x04000C0Cu);
    return p01 | p23;
}

// ---- W pre-convert: f32 ints -> i8, PRE-SWIZZLED tile-linear ---------------
// Wb = [bnb(4)][kt(16)] tiles [256 rows][64 cols] i8; linear glds fill leaves
// LDS 16B-slot s of row r holding element-slot s ^ ((r>>1)&3).
__global__ void wconv(const float* __restrict__ Wq, char* __restrict__ Wb) {
    const int n = blockIdx.x, c4 = threadIdx.x * 4;   // 1024 blocks x 256 thr
    float4 v = *(const float4*)(Wq + (size_t)n * K_TOTAL + c4);
    unsigned dw = pk4(v.x + MAGIC, v.y + MAGIC, v.z + MAGIC, v.w + MAGIC);
    const int bnb = n >> 8, row = n & 255, kt = c4 >> 6, c = c4 & 63;
    const int cs = (((c >> 4) ^ ((row >> 1) & 3)) << 4) + (c & 15);
    *(unsigned*)(Wb + (size_t)(bnb * NT + kt) * 16384 + row * 64 + cs) = dw;
}

// ---- main GEMM: 256x256, BK=64, 8 waves, 2-phase, i8 MFMA 16x16x64 ---------
__global__ __launch_bounds__(512, 2)
void qgemm(const float* __restrict__ X, const float* __restrict__ SXp,
           const char* __restrict__ Wb, const float* __restrict__ SW,
           const float* __restrict__ Bq, float* __restrict__ Out)
{
    __shared__ uint4 smem4[4096];          // 64 KiB: A dbuf @0, B dbuf @32768
    char* const smem = (char*)smem4;

    const int tid = threadIdx.x;

    // XCD-bijective remap: 4 bn-sharers of an X panel consecutive on one XCD
    const int d = blockIdx.x;
    const int g = (d & 7) * 128 + (d >> 3);
    const int bn_idx = g & 3, bm_idx = g >> 2;
    const int bm0 = bm_idx * BM, bn0 = bn_idx * BN;

    const float sx = SXp[0], inv_sx = 1.0f / sx;

    // A staging: thread -> row ar (+h*128), 16 f32 at col (tid&3)*16
    const int ar = tid >> 2;
    const int ac = (tid & 3) << 4;
    const float* xg = X + (size_t)(bm0 + ar) * K_TOTAL + ac;
    // write slot swizzle: (row>>1)&3 == (ar>>1)&3 (h*128 contributes 0 mod 4)
    const int aws = (((tid & 3) ^ ((ar >> 1) & 3)) << 4);

    // wave / fragment indices
    const int lane = tid & 63, w = tid >> 6;
    const int wm = (w >> 2) << 7, wn = (w & 3) << 6;
    const int fr = lane & 15, fg = lane >> 4;
    // read slot swizzle: (row>>1)&3 == (fr>>1)&3 for all fragment rows
    const int sslot = ((fg ^ ((fr >> 1) & 3)) << 4);
    const int arow = (wm + fr) * 64;       // A-tile row byte base
    const int brow = (wn + fr) * 64;       // B-tile row byte base

    // B glds: wave w fills rows w*32..w*32+31 (2 x 1024B instrs)
    const char* wsrc = Wb + (size_t)bn_idx * NT * 16384 + w * 2048 + lane * 16;

    i32x4 acc[8][4] = {};
    float4 xh0[4], xh1[4];
    i32x4 af[4], bf[4];

    auto issueA = [&](int kt, int h, float4* dst) {
        const float4* p = (const float4*)(xg + (size_t)h * 128 * K_TOTAL + kt * BK);
        dst[0] = p[0]; dst[1] = p[1]; dst[2] = p[2]; dst[3] = p[3];
    };
    auto packA = [&](int buf, int h, const float4* v) {
        unsigned u[4];
        #pragma unroll
        for (int q = 0; q < 4; ++q)
            u[q] = pk4(v[q].x * inv_sx + MAGIC, v[q].y * inv_sx + MAGIC,
                       v[q].z * inv_sx + MAGIC, v[q].w * inv_sx + MAGIC);
        char* base = smem + buf * 16384 + (h * 128 + ar) * 64;
        *(uint4*)(base + aws) = make_uint4(u[0], u[1], u[2], u[3]);
    };
    auto gldsB = [&](int kt, int buf) {
        const char* src = wsrc + (size_t)kt * 16384;
        char* dst = smem + 32768 + buf * 16384 + w * 2048;
        __builtin_amdgcn_global_load_lds((glb_vp*)(src +    0), (lds_vp*)(dst +    0), 16, 0, 0);
        __builtin_amdgcn_global_load_lds((glb_vp*)(src + 1024), (lds_vp*)(dst + 1024), 16, 0, 0);
    };
    auto readA = [&](int buf, int mh) {
        const char* base = smem + buf * 16384 + arow + sslot;
        #pragma unroll
        for (int i = 0; i < 4; ++i)
            af[i] = *(const i32x4*)(base + (mh * 64 + i * 16) * 64);
    };
    auto readB = [&](int buf) {
        const char* base = smem + 32768 + buf * 16384 + brow + sslot;
        #pragma unroll
        for (int j = 0; j < 4; ++j)
            bf[j] = *(const i32x4*)(base + (j * 16) * 64);
    };
    auto mfma16 = [&](int mh) {
        __builtin_amdgcn_s_setprio(1);
        #pragma unroll
        for (int i = 0; i < 4; ++i)
            #pragma unroll
            for (int j = 0; j < 4; ++j)
                acc[mh*4+i][j] = __builtin_amdgcn_mfma_i32_16x16x64_i8(
                    af[i], bf[j], acc[mh*4+i][j], 0, 0, 0);
        __builtin_amdgcn_s_setprio(0);
    };

    // ---- prologue: stage tile 0; issue A(1); counted wait for gldsB(0) ----
    issueA(0, 0, xh0); issueA(0, 1, xh1);
    gldsB(0, 0);
    packA(0, 0, xh0); packA(0, 1, xh1);    // reg-dep counted vmcnt, skips glds
    issueA(1, 0, xh0); issueA(1, 1, xh1);
    WAITV8();                              // queue [glds0 x2, A1 x8] -> glds done
    WAITL0();
    BAR();

    for (int t = 0; t < NT; ++t) {
        const int cur = t & 1, nxt = cur ^ 1;
        const bool pf  = (t + 1 < NT);
        const bool pf2 = (t + 2 < NT);
        // P0: gldsB(t+1) first (oldest); pack A(t+1,h0); reissue xh0<-A(t+2,h0)
        if (pf)  gldsB(t + 1, nxt);
        if (pf)  packA(nxt, 0, xh0);       // vmcnt(6): retires A(t+1,h0) only
        if (pf2) issueA(t + 2, 0, xh0);
        readA(cur, 0); readB(cur);
        BAR();
        mfma16(0);
        BAR();
        // P1: pack A(t+1,h1); reissue xh1<-A(t+2,h1); compute m4-7
        if (pf)  packA(nxt, 1, xh1);
        if (pf2) issueA(t + 2, 1, xh1);
        readA(cur, 1);
        BAR();
        mfma16(1);
        if (pf) {
            if (pf2) WAITV8();   // retire gldsB(t+1); keep A(t+2) x8 in flight
            else     WAITV0();   // t=14: only glds(15) left in queue
            WAITL0();            // packA ds_writes visible to all waves
            BAR();
        }
    }

    // epilogue: (acc_i32 + rint(b_int8/s_x)) * (s_w*s_x); exact: |acc|<2^24
    // C/D layout (dtype-independent): col=lane&15, row=(lane>>4)*4+r
    #pragma unroll
    for (int n = 0; n < 4; ++n) {
        const int col = bn0 + wn + n * 16 + fr;
        const float sa  = SW[col] * sx;
        const float b32 = rintf(Bq[col] * inv_sx);
        #pragma unroll
        for (int m = 0; m < 8; ++m) {
            const size_t r0 = (size_t)(bm0 + wm + m * 16 + fg * 4) * N_TOTAL + col;
            #pragma unroll
            for (int r = 0; r < 4; ++r)
                Out[r0 + (size_t)r * N_TOTAL] = ((float)acc[m][n][r] + b32) * sa;
        }
    }
}

__global__ void sa_tail(const float* __restrict__ SW, const float* __restrict__ SXp,
                        float* __restrict__ Out)
{
    int o = blockIdx.x * blockDim.x + threadIdx.x;
    if (o < N_TOTAL) Out[(size_t)M_TOTAL * N_TOTAL + o] = SW[o] * SXp[0];
}

extern "C" void kernel_launch(void* const* d_in, const int* in_sizes, int n_in,
                              void* d_out, int out_size, void* d_ws, size_t ws_size,
                              hipStream_t stream)
{
    const float* x  = (const float*)d_in[0];
    const float* sx = (const float*)d_in[1];
    const float* wq = (const float*)d_in[2];
    const float* sw = (const float*)d_in[3];
    const float* bq = (const float*)d_in[4];
    float* out = (float*)d_out;
    char* wbuf = (char*)d_ws;              // 1 MiB scratch

    wconv<<<1024, 256, 0, stream>>>(wq, wbuf);
    qgemm<<<(M_TOTAL / BM) * (N_TOTAL / BN), 512, 0, stream>>>(
        x, sx, wbuf, sw, bq, out);
    sa_tail<<<4, 256, 0, stream>>>(sw, sx, out);
}

// Round 7
// 236.039 us; speedup vs baseline: 1.0967x; 1.0967x over previous
//
#include <hip/hip_runtime.h>
#include <hip/hip_bf16.h>

#define M_TOTAL 65536
#define N_TOTAL 1024
#define K_TOTAL 1024

typedef __attribute__((ext_vector_type(8))) short short8;
typedef __attribute__((ext_vector_type(4))) float f32x4;
typedef __attribute__((ext_vector_type(4))) int   i32x4;

typedef __attribute__((address_space(3))) void lds_vp;
typedef const __attribute__((address_space(1))) void glb_vp;

#define BAR()    asm volatile("s_barrier" ::: "memory")
#define WAITV8() asm volatile("s_waitcnt vmcnt(8)" ::: "memory")
#define WAITV0() asm volatile("s_waitcnt vmcnt(0)" ::: "memory")
#define WAITL0() asm volatile("s_waitcnt lgkmcnt(0)" ::: "memory")

#define MAGIC 12582912.0f   // 1.5*2^23: low byte of (r+MAGIC) = (int8)rint(r)

static __device__ __forceinline__ unsigned fbits(float f) {
    union { float f; unsigned u; } c; c.f = f; return c.u;
}
// pack low bytes of 4 magic-biased floats into one dword (verified r6)
static __device__ __forceinline__ unsigned pk4(float g0, float g1, float g2, float g3) {
    unsigned p01 = __builtin_amdgcn_perm(fbits(g1), fbits(g0), 0x0C0C0400u);
    unsigned p23 = __builtin_amdgcn_perm(fbits(g3), fbits(g2), 0x04000C0Cu);
    return p01 | p23;
}
// non-contracted multiply: keep rint semantics of (v*inv) + MAGIC exact
static __device__ __forceinline__ float mulnc(float a, float b) {
    float t = a * b; asm volatile("" : "+v"(t)); return t;
}
// pack hi16 halves (bf16 of integer-valued f32) — fallback path
static __device__ __forceinline__ unsigned pkhi(float lo, float hi) {
    return __builtin_amdgcn_perm(fbits(hi), fbits(lo), 0x07060302u);
}

// ============================ FAST PATH (i8, ws>=66MB) =======================
// layouts: tiles [128 rows][64 cols] i8, pre-swizzled: logical 16B-slot s of
// row r stored at physical slot s ^ ((r>>1)&3). GEMM fills LDS linearly (glds).

// W: [1024][1024] f32 ints -> Wb [bnb(8)][kt(16)][128][64]
__global__ void wconv8(const float* __restrict__ Wq, char* __restrict__ Wb) {
    const int n = blockIdx.x, c4 = threadIdx.x * 4;   // 1024 x 256
    float4 v = *(const float4*)(Wq + (size_t)n * K_TOTAL + c4);
    unsigned dw = pk4(v.x + MAGIC, v.y + MAGIC, v.z + MAGIC, v.w + MAGIC);
    const int bnb = n >> 7, row = n & 127, kt = c4 >> 6, c = c4 & 63;
    const int cs = (((c >> 4) ^ ((row >> 1) & 3)) << 4) + (c & 15);
    *(unsigned*)(Wb + (size_t)(bnb * 16 + kt) * 8192 + row * 64 + cs) = dw;
}

// X: [65536][1024] f32 -> Xb [bmb(512)][kt(16)][128][64] i8 (quant + swizzle)
__global__ __launch_bounds__(256)
void xconv8(const float* __restrict__ X, const float* __restrict__ SXp,
            char* __restrict__ Xb) {
    const float inv_sx = 1.0f / SXp[0];
    const unsigned gid = blockIdx.x * 256 + threadIdx.x;  // 4,194,304 total
    const int slot = gid & 3;
    const int row  = (gid >> 2) & 127;
    const int kt   = (gid >> 9) & 15;
    const int bmb  = gid >> 13;
    const float* src = X + (size_t)(bmb * 128 + row) * K_TOTAL + kt * 64 + slot * 16;
    unsigned u[4];
    #pragma unroll
    for (int q = 0; q < 4; ++q) {
        float4 v = *(const float4*)(src + q * 4);
        u[q] = pk4(mulnc(v.x, inv_sx) + MAGIC, mulnc(v.y, inv_sx) + MAGIC,
                   mulnc(v.z, inv_sx) + MAGIC, mulnc(v.w, inv_sx) + MAGIC);
    }
    const int p = slot ^ ((row >> 1) & 3);
    *(uint4*)(Xb + (size_t)(bmb * 16 + kt) * 8192 + row * 64 + p * 16) =
        make_uint4(u[0], u[1], u[2], u[3]);
}

// GEMM: 128x128 tile, BK=64, 4 waves, pure-glds staging, 4 blocks/CU
__global__ __launch_bounds__(256, 4)
void qgemm8(const char* __restrict__ Xb, const float* __restrict__ SXp,
            const char* __restrict__ Wb, const float* __restrict__ SW,
            const float* __restrict__ Bq, float* __restrict__ Out)
{
    __shared__ uint4 smem4[2048];          // 32 KiB: A dbuf @0, B dbuf @16384
    char* const smem = (char*)smem4;

    const int tid = threadIdx.x;
    // XCD remap: nwg=4096, 512/XCD; bn fastest -> 8 bn-sharers on same XCD
    const int d = blockIdx.x;
    const int g = (d & 7) * 512 + (d >> 3);
    const int bn_idx = g & 7, bm_idx = g >> 3;

    const float sx = SXp[0], inv_sx = 1.0f / sx;

    const int lane = tid & 63, w = tid >> 6;
    const int wm = (w >> 1) << 6, wn = (w & 1) << 6;
    const int fr = lane & 15, fg = lane >> 4;
    const int sslot = ((fg ^ ((fr >> 1) & 3)) << 4);
    const int arow = (wm + fr) * 64;
    const int brow = (wn + fr) * 64;

    // glds sources: wave w covers bytes [w*2048, w*2048+2048) of each 8KB tile
    const char* asrc = Xb + (size_t)bm_idx * 16 * 8192 + w * 2048 + lane * 16;
    const char* bsrc = Wb + (size_t)bn_idx * 16 * 8192 + w * 2048 + lane * 16;

    i32x4 acc[4][4] = {};
    i32x4 af[4], bf[4];

    auto glds = [&](int kt, int buf) {
        const char* sa = asrc + (size_t)kt * 8192;
        const char* sb = bsrc + (size_t)kt * 8192;
        char* da = smem +         buf * 8192 + w * 2048;
        char* db = smem + 16384 + buf * 8192 + w * 2048;
        __builtin_amdgcn_global_load_lds((glb_vp*)(sa +    0), (lds_vp*)(da +    0), 16, 0, 0);
        __builtin_amdgcn_global_load_lds((glb_vp*)(sa + 1024), (lds_vp*)(da + 1024), 16, 0, 0);
        __builtin_amdgcn_global_load_lds((glb_vp*)(sb +    0), (lds_vp*)(db +    0), 16, 0, 0);
        __builtin_amdgcn_global_load_lds((glb_vp*)(sb + 1024), (lds_vp*)(db + 1024), 16, 0, 0);
    };

    // prologue
    glds(0, 0);
    WAITV0();
    BAR();

    for (int t = 0; t < 16; ++t) {
        const int cur = t & 1;
        const bool pf = (t + 1 < 16);
        if (pf) glds(t + 1, cur ^ 1);     // issue first (covered by reads+mfma)
        {
            const char* ab = smem + cur * 8192 + arow + sslot;
            const char* bb = smem + 16384 + cur * 8192 + brow + sslot;
            #pragma unroll
            for (int i = 0; i < 4; ++i)
                af[i] = *(const i32x4*)(ab + (i * 16) * 64);
            #pragma unroll
            for (int j = 0; j < 4; ++j)
                bf[j] = *(const i32x4*)(bb + (j * 16) * 64);
        }
        __builtin_amdgcn_s_setprio(1);
        #pragma unroll
        for (int i = 0; i < 4; ++i)
            #pragma unroll
            for (int j = 0; j < 4; ++j)
                acc[i][j] = __builtin_amdgcn_mfma_i32_16x16x64_i8(
                    af[i], bf[j], acc[i][j], 0, 0, 0);
        __builtin_amdgcn_s_setprio(0);
        if (pf) { WAITV0(); BAR(); }       // glds(t+1) complete & visible
    }

    // epilogue: (acc_i32 + rint(b/s_x)) * (s_w*s_x); exact (|acc|+|b32| < 2^24)
    const int bm0 = bm_idx * 128, bn0 = bn_idx * 128;
    #pragma unroll
    for (int n = 0; n < 4; ++n) {
        const int col = bn0 + wn + n * 16 + fr;
        const float sa  = SW[col] * sx;
        const float b32 = rintf(Bq[col] * inv_sx);
        #pragma unroll
        for (int m = 0; m < 4; ++m) {
            const size_t r0 = (size_t)(bm0 + wm + m * 16 + fg * 4) * N_TOTAL + col;
            #pragma unroll
            for (int r = 0; r < 4; ++r)
                Out[r0 + (size_t)r * N_TOTAL] = ((float)acc[m][n][r] + b32) * sa;
        }
    }
}

// ===================== FALLBACK (r5 bf16 kernel, 221us) ======================
__global__ void wconv_bf(const float* __restrict__ Wq, ushort* __restrict__ Wb) {
    const int n = blockIdx.x, c4 = threadIdx.x * 4;
    float4 v = *(const float4*)(Wq + (size_t)n * K_TOTAL + c4);
    const int bnb = n >> 8, row = n & 255, kt = c4 >> 6, c = c4 & 63;
    const int cs = c ^ ((row & 7) << 3);
    ushort* dst = Wb + ((size_t)(bnb * 16 + kt) * 16384 + row * 64 + cs);
    *(uint2*)dst = make_uint2(pkhi(v.x, v.y), pkhi(v.z, v.w));
}

__global__ __launch_bounds__(512, 2)
void qgemm_bf(const float* __restrict__ X, const float* __restrict__ SXp,
              const ushort* __restrict__ Wb, const float* __restrict__ SW,
              const float* __restrict__ Bq, float* __restrict__ Out)
{
    __shared__ uint4 smem4[8192];
    char* const smem = (char*)smem4;
    const int tid = threadIdx.x;
    const int d = blockIdx.x;
    const int g = (d & 7) * 128 + (d >> 3);
    const int bn_idx = g & 3, bm_idx = g >> 2;
    const int bm0 = bm_idx * 256, bn0 = bn_idx * 256;
    const float sx = SXp[0], inv_sx = 1.0f / sx;
    const int ar = tid >> 2, ac = (tid & 3) << 4;
    const float* xg = X + (size_t)(bm0 + ar) * K_TOTAL + ac;
    const int awslot = (tid & 3) << 1;
    const int awsw0 = ((awslot    ) ^ (ar & 7)) << 4;
    const int awsw1 = ((awslot + 1) ^ (ar & 7)) << 4;
    const int lane = tid & 63, w = tid >> 6;
    const int wm = (w >> 2) << 7, wn = (w & 3) << 6;
    const int fr = lane & 15, fg = lane >> 4;
    const int s0 = ((fg    ) ^ (fr & 7)) << 4;
    const int s1 = ((fg + 4) ^ (fr & 7)) << 4;
    const int arow = (wm + fr) * 128, brow = (wn + fr) * 128;
    const char* wsrc = (const char*)Wb + (size_t)bn_idx * 16 * 32768
                     + w * 4096 + lane * 16;
    f32x4 acc[8][4] = {};
    float4 xh0[4], xh1[4];
    short8 af[4], bf[4];
    auto issueA = [&](int kt, int h, float4* dst) {
        const float4* p = (const float4*)(xg + (size_t)h * 128 * K_TOTAL + kt * 64);
        dst[0] = p[0]; dst[1] = p[1]; dst[2] = p[2]; dst[3] = p[3];
    };
    auto packA = [&](int buf, int h, const float4* v) {
        unsigned u[8];
        #pragma unroll
        for (int q = 0; q < 4; ++q) {
            u[2*q+0] = pkhi(rintf(v[q].x * inv_sx), rintf(v[q].y * inv_sx));
            u[2*q+1] = pkhi(rintf(v[q].z * inv_sx), rintf(v[q].w * inv_sx));
        }
        char* base = smem + buf * 32768 + (h * 128 + ar) * 128;
        *(uint4*)(base + awsw0) = make_uint4(u[0], u[1], u[2], u[3]);
        *(uint4*)(base + awsw1) = make_uint4(u[4], u[5], u[6], u[7]);
    };
    auto gldsB = [&](int kt, int buf) {
        const char* src = wsrc + (size_t)kt * 32768;
        char* dst = smem + 65536 + buf * 32768 + w * 4096;
        __builtin_amdgcn_global_load_lds((glb_vp*)(src +    0), (lds_vp*)(dst +    0), 16, 0, 0);
        __builtin_amdgcn_global_load_lds((glb_vp*)(src + 1024), (lds_vp*)(dst + 1024), 16, 0, 0);
        __builtin_amdgcn_global_load_lds((glb_vp*)(src + 2048), (lds_vp*)(dst + 2048), 16, 0, 0);
        __builtin_amdgcn_global_load_lds((glb_vp*)(src + 3072), (lds_vp*)(dst + 3072), 16, 0, 0);
    };
    auto readA = [&](int buf, int mh, int sk) {
        const char* base = smem + buf * 32768 + arow;
        #pragma unroll
        for (int i = 0; i < 4; ++i)
            af[i] = *(const short8*)(base + (mh * 64 + i * 16) * 128 + sk);
    };
    auto readB = [&](int buf, int sk) {
        const char* base = smem + 65536 + buf * 32768 + brow;
        #pragma unroll
        for (int j = 0; j < 4; ++j)
            bf[j] = *(const short8*)(base + (j * 16) * 128 + sk);
    };
    auto mfma16 = [&](int mh) {
        __builtin_amdgcn_s_setprio(1);
        #pragma unroll
        for (int i = 0; i < 4; ++i)
            #pragma unroll
            for (int j = 0; j < 4; ++j)
                acc[mh*4+i][j] = __builtin_amdgcn_mfma_f32_16x16x32_bf16(
                    af[i], bf[j], acc[mh*4+i][j], 0, 0, 0);
        __builtin_amdgcn_s_setprio(0);
    };
    issueA(0, 0, xh0); issueA(0, 1, xh1);
    gldsB(0, 0);
    packA(0, 0, xh0); packA(0, 1, xh1);
    issueA(1, 0, xh0); issueA(1, 1, xh1);
    WAITV8(); WAITL0(); BAR();
    for (int t = 0; t < 16; ++t) {
        const int cur = t & 1, nxt = cur ^ 1;
        const bool pf  = (t + 1 < 16);
        const bool pf2 = (t + 2 < 16);
        if (pf) gldsB(t + 1, nxt);
        readA(cur, 0, s0); readB(cur, s0);
        BAR(); mfma16(0); BAR();
        readA(cur, 1, s0);
        BAR(); mfma16(1); BAR();
        if (pf)  packA(nxt, 0, xh0);
        if (pf2) issueA(t + 2, 0, xh0);
        readA(cur, 0, s1); readB(cur, s1);
        BAR(); mfma16(0); BAR();
        if (pf)  packA(nxt, 1, xh1);
        if (pf2) issueA(t + 2, 1, xh1);
        readA(cur, 1, s1);
        BAR(); mfma16(1);
        if (pf) {
            if (pf2) WAITV8(); else WAITV0();
            WAITL0(); BAR();
        }
    }
    #pragma unroll
    for (int n = 0; n < 4; ++n) {
        const int col = bn0 + wn + n * 16 + fr;
        const float sa  = SW[col] * sx;
        const float b32 = rintf(Bq[col] * inv_sx);
        #pragma unroll
        for (int m = 0; m < 8; ++m) {
            const size_t r0 = (size_t)(bm0 + wm + m * 16 + fg * 4) * N_TOTAL + col;
            #pragma unroll
            for (int r = 0; r < 4; ++r)
                Out[r0 + (size_t)r * N_TOTAL] = (acc[m][n][r] + b32) * sa;
        }
    }
}

__global__ void sa_tail(const float* __restrict__ SW, const float* __restrict__ SXp,
                        float* __restrict__ Out)
{
    int o = blockIdx.x * blockDim.x + threadIdx.x;
    if (o < N_TOTAL) Out[(size_t)M_TOTAL * N_TOTAL + o] = SW[o] * SXp[0];
}

extern "C" void kernel_launch(void* const* d_in, const int* in_sizes, int n_in,
                              void* d_out, int out_size, void* d_ws, size_t ws_size,
                              hipStream_t stream)
{
    const float* x  = (const float*)d_in[0];
    const float* sx = (const float*)d_in[1];
    const float* wq = (const float*)d_in[2];
    const float* sw = (const float*)d_in[3];
    const float* bq = (const float*)d_in[4];
    float* out = (float*)d_out;

    const size_t W_BYTES = 1u << 20;          // Wb: 1 MiB
    const size_t X_BYTES = (size_t)64 << 20;  // Xb: 64 MiB

    if (ws_size >= W_BYTES + X_BYTES) {
        char* wbuf = (char*)d_ws;
        char* xbuf = (char*)d_ws + W_BYTES;
        wconv8<<<1024, 256, 0, stream>>>(wq, wbuf);
        xconv8<<<16384, 256, 0, stream>>>(x, sx, xbuf);
        qgemm8<<<4096, 256, 0, stream>>>(xbuf, sx, wbuf, sw, bq, out);
    } else {
        ushort* wbuf = (ushort*)d_ws;         // 2 MiB (r5 path)
        wconv_bf<<<1024, 256, 0, stream>>>(wq, wbuf);
        qgemm_bf<<<1024, 512, 0, stream>>>(x, sx, wbuf, sw, bq, out);
    }
    sa_tail<<<4, 256, 0, stream>>>(sw, sx, out);
}